// Round 1
// baseline (345.930 us; speedup 1.0000x reference)
//
#include <hip/hip_runtime.h>
#include <hip/hip_bf16.h>

#define NH 12
#define HD 64
#define SEQ 2048
#define DM 768

typedef __attribute__((ext_vector_type(8))) short bf16x8;
typedef __attribute__((ext_vector_type(4))) float f32x4;

static __device__ __forceinline__ unsigned short f2bf(float f) {
  unsigned int u = __float_as_uint(f);
  u += 0x7fff + ((u >> 16) & 1);   // round-to-nearest-even
  return (unsigned short)(u >> 16);
}

// ---------------------------------------------------------------------------
// Kernel 1: qkv = x @ W^T + b   (M=8192, N=1536, K=768), split-store q/v as
// bf16 in (B,H,S,HD) layout. 128x128 tile, BK=32, 4 waves (2x2) of 64x64.
// ---------------------------------------------------------------------------
__global__ __launch_bounds__(256) void qkv_kernel(
    const float* __restrict__ x, const float* __restrict__ w,
    const float* __restrict__ bias,
    unsigned short* __restrict__ qb, unsigned short* __restrict__ vb) {
  __shared__ alignas(16) unsigned short As[128 * 40];  // +8 pad: 20-bank row stride
  __shared__ alignas(16) unsigned short Bs[128 * 40];
  const int tid = threadIdx.x;
  const int lane = tid & 63, wid = tid >> 6;
  const int wr = wid >> 1, wc = wid & 1;
  const int g = lane >> 4, c = lane & 15;
  const int m0 = blockIdx.x * 128, n0 = blockIdx.y * 128;

  f32x4 acc[4][4] = {};

  for (int k0 = 0; k0 < DM; k0 += 32) {
#pragma unroll
    for (int i = 0; i < 4; ++i) {
      const int idx = tid + i * 256;
      const int row = idx >> 3, kq = (idx & 7) << 2;
      const float4 va = *reinterpret_cast<const float4*>(&x[(m0 + row) * DM + k0 + kq]);
      const float4 vw = *reinterpret_cast<const float4*>(&w[(n0 + row) * DM + k0 + kq]);
      *reinterpret_cast<ushort4*>(&As[row * 40 + kq]) =
          make_ushort4(f2bf(va.x), f2bf(va.y), f2bf(va.z), f2bf(va.w));
      *reinterpret_cast<ushort4*>(&Bs[row * 40 + kq]) =
          make_ushort4(f2bf(vw.x), f2bf(vw.y), f2bf(vw.z), f2bf(vw.w));
    }
    __syncthreads();
    bf16x8 a_f[4], b_f[4];
#pragma unroll
    for (int i = 0; i < 4; ++i) {
      a_f[i] = *reinterpret_cast<const bf16x8*>(&As[(wr * 64 + i * 16 + c) * 40 + g * 8]);
      b_f[i] = *reinterpret_cast<const bf16x8*>(&Bs[(wc * 64 + i * 16 + c) * 40 + g * 8]);
    }
#pragma unroll
    for (int ai = 0; ai < 4; ++ai)
#pragma unroll
      for (int ni = 0; ni < 4; ++ni)
        acc[ai][ni] = __builtin_amdgcn_mfma_f32_16x16x32_bf16(a_f[ai], b_f[ni], acc[ai][ni], 0, 0, 0);
    __syncthreads();
  }

#pragma unroll
  for (int ni = 0; ni < 4; ++ni) {
    const int n = n0 + wc * 64 + ni * 16 + c;
    const float bn = bias[n];
    unsigned short* dst = (n < DM) ? qb : vb;
    const int nn = (n < DM) ? n : (n - DM);
    const int h = nn >> 6, d = nn & 63;
#pragma unroll
    for (int ai = 0; ai < 4; ++ai) {
#pragma unroll
      for (int r = 0; r < 4; ++r) {
        const int m = m0 + wr * 64 + ai * 16 + g * 4 + r;  // C layout: row=(lane>>4)*4+r
        const int bb = m >> 11, s = m & 2047;
        dst[(((size_t)(bb * NH + h)) * SEQ + s) * HD + d] = f2bf(acc[ai][ni][r] + bn);
      }
    }
  }
}

// ---------------------------------------------------------------------------
// Kernel 2: flash attention with Q == K (shared tensor), logits = (q.q)/64.
// Block = 4 waves, 64 Q-rows per block (16 rows/wave), K-tiles of 64.
// ---------------------------------------------------------------------------
__global__ __launch_bounds__(256) void attn_kernel(
    const unsigned short* __restrict__ qb, const unsigned short* __restrict__ vb,
    unsigned short* __restrict__ ao) {
  __shared__ alignas(16) unsigned short Qs[64 * 72];  // +8 pad
  __shared__ alignas(16) unsigned short Ks[64 * 72];
  __shared__ alignas(16) unsigned short Vt[64 * 72];  // transposed: [d][j]
  __shared__ alignas(16) unsigned short Ps[64 * 72];

  const int tid = threadIdx.x;
  const int lane = tid & 63, wid = tid >> 6;
  const int g = lane >> 4, c = lane & 15;
  const int bh = blockIdx.y;
  const int b = bh / NH, h = bh % NH;
  const int qs0 = blockIdx.x * 64;
  const size_t base = (size_t)bh * SEQ * HD;

  {  // stage Q tile once
    const int row = tid >> 2, dq = (tid & 3) << 4;
    const unsigned short* src = &qb[base + (size_t)(qs0 + row) * HD + dq];
    *reinterpret_cast<bf16x8*>(&Qs[row * 72 + dq]) = *reinterpret_cast<const bf16x8*>(src);
    *reinterpret_cast<bf16x8*>(&Qs[row * 72 + dq + 8]) = *reinterpret_cast<const bf16x8*>(src + 8);
  }

  float m_r[4] = {-1e30f, -1e30f, -1e30f, -1e30f};
  float l_r[4] = {0.f, 0.f, 0.f, 0.f};
  f32x4 o_acc[4] = {};

  __syncthreads();

  for (int kt = 0; kt < 32; ++kt) {
    const int ks0 = kt * 64;
    {  // stage K tile (K == Q tensor)
      const int row = tid >> 2, dq = (tid & 3) << 4;
      const unsigned short* src = &qb[base + (size_t)(ks0 + row) * HD + dq];
      *reinterpret_cast<bf16x8*>(&Ks[row * 72 + dq]) = *reinterpret_cast<const bf16x8*>(src);
      *reinterpret_cast<bf16x8*>(&Ks[row * 72 + dq + 8]) = *reinterpret_cast<const bf16x8*>(src + 8);
    }
#pragma unroll
    for (int i = 0; i < 2; ++i) {  // stage V transposed
      const int idx = tid + i * 256;
      const int row = idx >> 3, dq = (idx & 7) << 3;
      bf16x8 vv = *reinterpret_cast<const bf16x8*>(&vb[base + (size_t)(ks0 + row) * HD + dq]);
#pragma unroll
      for (int e = 0; e < 8; ++e)
        Vt[(dq + e) * 72 + row] = ((unsigned short*)&vv)[e];
    }
    __syncthreads();

    // S = Q K^T  (each wave: rows wid*16..+15, all 64 cols)
    f32x4 s_acc[4] = {};
#pragma unroll
    for (int ks = 0; ks < 2; ++ks) {
      const bf16x8 aq = *reinterpret_cast<const bf16x8*>(&Qs[(wid * 16 + c) * 72 + ks * 32 + g * 8]);
#pragma unroll
      for (int j = 0; j < 4; ++j) {
        const bf16x8 bk = *reinterpret_cast<const bf16x8*>(&Ks[(j * 16 + c) * 72 + ks * 32 + g * 8]);
        s_acc[j] = __builtin_amdgcn_mfma_f32_16x16x32_bf16(aq, bk, s_acc[j], 0, 0, 0);
      }
    }
#pragma unroll
    for (int j = 0; j < 4; ++j) s_acc[j] *= 0.015625f;  // SCALE^2 = 1/64, exact pow2

    // online softmax; C layout: row = g*4+r, col = j*16+c -> reduce over 16 lanes
    float p[4][4];
    float alpha[4];
#pragma unroll
    for (int r = 0; r < 4; ++r) {
      float tm = fmaxf(fmaxf(s_acc[0][r], s_acc[1][r]), fmaxf(s_acc[2][r], s_acc[3][r]));
#pragma unroll
      for (int off = 1; off < 16; off <<= 1) tm = fmaxf(tm, __shfl_xor(tm, off, 16));
      const float mnew = fmaxf(m_r[r], tm);
      alpha[r] = __expf(m_r[r] - mnew);
      m_r[r] = mnew;
      float rs = 0.f;
#pragma unroll
      for (int j = 0; j < 4; ++j) { p[j][r] = __expf(s_acc[j][r] - mnew); rs += p[j][r]; }
#pragma unroll
      for (int off = 1; off < 16; off <<= 1) rs += __shfl_xor(rs, off, 16);
      l_r[r] = l_r[r] * alpha[r] + rs;
    }
#pragma unroll
    for (int dn = 0; dn < 4; ++dn)
#pragma unroll
      for (int r = 0; r < 4; ++r) o_acc[dn][r] *= alpha[r];

#pragma unroll
    for (int j = 0; j < 4; ++j)
#pragma unroll
      for (int r = 0; r < 4; ++r)
        Ps[(wid * 16 + g * 4 + r) * 72 + j * 16 + c] = f2bf(p[j][r]);
    __syncthreads();

    // O += P V   (B-frag from Vt is contiguous)
#pragma unroll
    for (int ks = 0; ks < 2; ++ks) {
      const bf16x8 ap = *reinterpret_cast<const bf16x8*>(&Ps[(wid * 16 + c) * 72 + ks * 32 + g * 8]);
#pragma unroll
      for (int dn = 0; dn < 4; ++dn) {
        const bf16x8 bv = *reinterpret_cast<const bf16x8*>(&Vt[(dn * 16 + c) * 72 + ks * 32 + g * 8]);
        o_acc[dn] = __builtin_amdgcn_mfma_f32_16x16x32_bf16(ap, bv, o_acc[dn], 0, 0, 0);
      }
    }
    __syncthreads();
  }

  // epilogue: normalize and store to (B,S,D) bf16
#pragma unroll
  for (int dn = 0; dn < 4; ++dn) {
#pragma unroll
    for (int r = 0; r < 4; ++r) {
      const int srow = qs0 + wid * 16 + g * 4 + r;
      const int col = h * HD + dn * 16 + c;
      ao[((size_t)b * SEQ + srow) * DM + col] = f2bf(o_acc[dn][r] / l_r[r]);
    }
  }
}

// ---------------------------------------------------------------------------
// Kernel 3: out = ao @ proj_w^T + proj_b  (M=8192, N=768, K=768), f32 out.
// ---------------------------------------------------------------------------
__global__ __launch_bounds__(256) void proj_kernel(
    const unsigned short* __restrict__ ao, const float* __restrict__ w,
    const float* __restrict__ bias, float* __restrict__ out) {
  __shared__ alignas(16) unsigned short As[128 * 40];
  __shared__ alignas(16) unsigned short Bs[128 * 40];
  const int tid = threadIdx.x;
  const int lane = tid & 63, wid = tid >> 6;
  const int wr = wid >> 1, wc = wid & 1;
  const int g = lane >> 4, c = lane & 15;
  const int m0 = blockIdx.x * 128, n0 = blockIdx.y * 128;

  f32x4 acc[4][4] = {};

  for (int k0 = 0; k0 < DM; k0 += 32) {
#pragma unroll
    for (int i = 0; i < 2; ++i) {  // A: bf16 copy
      const int idx = tid + i * 256;
      const int row = idx >> 2, kq = (idx & 3) << 3;
      *reinterpret_cast<bf16x8*>(&As[row * 40 + kq]) =
          *reinterpret_cast<const bf16x8*>(&ao[(m0 + row) * DM + k0 + kq]);
    }
#pragma unroll
    for (int i = 0; i < 4; ++i) {  // B: f32 -> bf16
      const int idx = tid + i * 256;
      const int row = idx >> 3, kq = (idx & 7) << 2;
      const float4 vw = *reinterpret_cast<const float4*>(&w[(n0 + row) * DM + k0 + kq]);
      *reinterpret_cast<ushort4*>(&Bs[row * 40 + kq]) =
          make_ushort4(f2bf(vw.x), f2bf(vw.y), f2bf(vw.z), f2bf(vw.w));
    }
    __syncthreads();
    bf16x8 a_f[4], b_f[4];
#pragma unroll
    for (int i = 0; i < 4; ++i) {
      a_f[i] = *reinterpret_cast<const bf16x8*>(&As[(wr * 64 + i * 16 + c) * 40 + g * 8]);
      b_f[i] = *reinterpret_cast<const bf16x8*>(&Bs[(wc * 64 + i * 16 + c) * 40 + g * 8]);
    }
#pragma unroll
    for (int ai = 0; ai < 4; ++ai)
#pragma unroll
      for (int ni = 0; ni < 4; ++ni)
        acc[ai][ni] = __builtin_amdgcn_mfma_f32_16x16x32_bf16(a_f[ai], b_f[ni], acc[ai][ni], 0, 0, 0);
    __syncthreads();
  }

#pragma unroll
  for (int ni = 0; ni < 4; ++ni) {
    const int n = n0 + wc * 64 + ni * 16 + c;
    const float bn = bias[n];
#pragma unroll
    for (int ai = 0; ai < 4; ++ai)
#pragma unroll
      for (int r = 0; r < 4; ++r) {
        const int m = m0 + wr * 64 + ai * 16 + g * 4 + r;
        out[(size_t)m * DM + n] = acc[ai][ni][r] + bn;
      }
  }
}

extern "C" void kernel_launch(void* const* d_in, const int* in_sizes, int n_in,
                              void* d_out, int out_size, void* d_ws, size_t ws_size,
                              hipStream_t stream) {
  const float* x = (const float*)d_in[0];
  const float* qkv_w = (const float*)d_in[1];
  const float* qkv_b = (const float*)d_in[2];
  const float* proj_w = (const float*)d_in[3];
  const float* proj_b = (const float*)d_in[4];
  float* out = (float*)d_out;

  const size_t elems = (size_t)4 * NH * SEQ * HD;  // 6291456
  unsigned short* qbuf = (unsigned short*)d_ws;
  unsigned short* vbuf = qbuf + elems;
  unsigned short* aobuf = vbuf + elems;

  qkv_kernel<<<dim3(64, 12), 256, 0, stream>>>(x, qkv_w, qkv_b, qbuf, vbuf);
  attn_kernel<<<dim3(32, 48), 256, 0, stream>>>(qbuf, vbuf, aobuf);
  proj_kernel<<<dim3(64, 6), 256, 0, stream>>>(aobuf, proj_w, proj_b, out);
}

// Round 2
// 278.507 us; speedup vs baseline: 1.2421x; 1.2421x over previous
//
#include <hip/hip_runtime.h>
#include <hip/hip_bf16.h>

#define NH 12
#define HD 64
#define SEQ 2048
#define DM 768

typedef __attribute__((ext_vector_type(8))) short bf16x8;
typedef __attribute__((ext_vector_type(4))) float f32x4;

static __device__ __forceinline__ unsigned short f2bf(float f) {
  unsigned int u = __float_as_uint(f);
  u += 0x7fff + ((u >> 16) & 1);   // round-to-nearest-even
  return (unsigned short)(u >> 16);
}

static __device__ __forceinline__ void gload_lds16(const void* g, void* l) {
  __builtin_amdgcn_global_load_lds(
      (const __attribute__((address_space(1))) void*)g,
      (__attribute__((address_space(3))) void*)l, 16, 0, 0);
}

// ---------------------------------------------------------------------------
// Kernel 1: qkv = x @ W^T + b   (M=8192, N=1536, K=768). q stored (B,H,S,HD)
// bf16; v stored TRANSPOSED (B,H,HD,S) bf16 so attention PV needs no LDS
// transpose. 128x128 tile, BK=32, 4 waves (2x2) of 64x64.
// ---------------------------------------------------------------------------
__global__ __launch_bounds__(256) void qkv_kernel(
    const float* __restrict__ x, const float* __restrict__ w,
    const float* __restrict__ bias,
    unsigned short* __restrict__ qb, unsigned short* __restrict__ vtb) {
  __shared__ alignas(16) unsigned short As[128 * 40];  // +8 pad
  __shared__ alignas(16) unsigned short Bs[128 * 40];
  const int tid = threadIdx.x;
  const int lane = tid & 63, wid = tid >> 6;
  const int wr = wid >> 1, wc = wid & 1;
  const int g = lane >> 4, c = lane & 15;
  const int m0 = blockIdx.x * 128, n0 = blockIdx.y * 128;

  f32x4 acc[4][4] = {};

  for (int k0 = 0; k0 < DM; k0 += 32) {
#pragma unroll
    for (int i = 0; i < 4; ++i) {
      const int idx = tid + i * 256;
      const int row = idx >> 3, kq = (idx & 7) << 2;
      const float4 va = *reinterpret_cast<const float4*>(&x[(m0 + row) * DM + k0 + kq]);
      const float4 vw = *reinterpret_cast<const float4*>(&w[(n0 + row) * DM + k0 + kq]);
      *reinterpret_cast<ushort4*>(&As[row * 40 + kq]) =
          make_ushort4(f2bf(va.x), f2bf(va.y), f2bf(va.z), f2bf(va.w));
      *reinterpret_cast<ushort4*>(&Bs[row * 40 + kq]) =
          make_ushort4(f2bf(vw.x), f2bf(vw.y), f2bf(vw.z), f2bf(vw.w));
    }
    __syncthreads();
    bf16x8 a_f[4], b_f[4];
#pragma unroll
    for (int i = 0; i < 4; ++i) {
      a_f[i] = *reinterpret_cast<const bf16x8*>(&As[(wr * 64 + i * 16 + c) * 40 + g * 8]);
      b_f[i] = *reinterpret_cast<const bf16x8*>(&Bs[(wc * 64 + i * 16 + c) * 40 + g * 8]);
    }
#pragma unroll
    for (int ai = 0; ai < 4; ++ai)
#pragma unroll
      for (int ni = 0; ni < 4; ++ni)
        acc[ai][ni] = __builtin_amdgcn_mfma_f32_16x16x32_bf16(a_f[ai], b_f[ni], acc[ai][ni], 0, 0, 0);
    __syncthreads();
  }

#pragma unroll
  for (int ni = 0; ni < 4; ++ni) {
    const int n = n0 + wc * 64 + ni * 16 + c;
    const float bn = bias[n];
    if (n < DM) {  // q path: (B,H,S,HD)
      const int h = n >> 6, d = n & 63;
#pragma unroll
      for (int ai = 0; ai < 4; ++ai)
#pragma unroll
        for (int r = 0; r < 4; ++r) {
          const int m = m0 + wr * 64 + ai * 16 + g * 4 + r;
          const int bb = m >> 11, s = m & 2047;
          qb[(((size_t)(bb * NH + h)) * SEQ + s) * HD + d] = f2bf(acc[ai][ni][r] + bn);
        }
    } else {  // v path: transposed (B,H,HD,S); 4 consecutive s -> packed store
      const int nn = n - DM;
      const int h = nn >> 6, d = nn & 63;
#pragma unroll
      for (int ai = 0; ai < 4; ++ai) {
        const int m_base = m0 + wr * 64 + ai * 16 + g * 4;
        const int bb = m_base >> 11, s0 = m_base & 2047;
        ushort4 pk = make_ushort4(f2bf(acc[ai][ni][0] + bn), f2bf(acc[ai][ni][1] + bn),
                                  f2bf(acc[ai][ni][2] + bn), f2bf(acc[ai][ni][3] + bn));
        *reinterpret_cast<ushort4*>(
            &vtb[((size_t)(bb * NH + h) * HD + d) * SEQ + s0]) = pk;
      }
    }
  }
}

// ---------------------------------------------------------------------------
// Kernel 2: flash attention, Q == K, logits = (q.q)/64.
// 4 waves, 64 Q-rows/block, K-tiles of 64. Double-buffered global_load_lds
// staging of K and V^T with XOR-swizzled layout; raw barriers with counted
// waitcnt so prefetch loads stay in flight across the mid barrier.
// ---------------------------------------------------------------------------
__global__ __launch_bounds__(256) void attn_kernel(
    const unsigned short* __restrict__ qb, const unsigned short* __restrict__ vtb,
    unsigned short* __restrict__ ao) {
  __shared__ alignas(16) unsigned short Qs[64 * 72];      // padded, vector-written
  __shared__ alignas(16) unsigned short Ks[2][64 * 64];   // linear + XOR swizzle
  __shared__ alignas(16) unsigned short Vt[2][64 * 64];   // V^T tile, same swizzle
  __shared__ alignas(16) unsigned short Ps[64 * 72];      // col-bit4 XOR swizzle

  const int tid = threadIdx.x;
  const int lane = tid & 63, wid = tid >> 6;
  const int g = lane >> 4, c = lane & 15;
  const int bh = blockIdx.y;
  const int qs0 = blockIdx.x * 64;
  const size_t base = (size_t)bh * SEQ * HD;  // ushort index into qb

  {  // stage Q tile once (padded stride 72 -> conflict-free frag reads)
    const int row = tid >> 2, dq = (tid & 3) << 4;
    const unsigned short* src = &qb[base + (size_t)(qs0 + row) * HD + dq];
    *reinterpret_cast<bf16x8*>(&Qs[row * 72 + dq]) = *reinterpret_cast<const bf16x8*>(src);
    *reinterpret_cast<bf16x8*>(&Qs[row * 72 + dq + 8]) = *reinterpret_cast<const bf16x8*>(src + 8);
  }

  // async stage of K-tile + V^T-tile kt into buffer buf (linear LDS dest,
  // inverse-swizzled global source; involution byte ^= ((row&7)<<4))
  const char* qb_bytes = (const char*)qb;
  const char* vt_bytes = (const char*)vtb;
  auto stage = [&](int kt, int buf) {
    const int ks0 = kt * 64;
    const size_t ktile_byte = (base + (size_t)ks0 * HD) * 2;  // contiguous 8KB
#pragma unroll
    for (int i = 0; i < 2; ++i) {
      const int o = tid * 16 + i * 4096;
      const int swz = o ^ (((o >> 7) & 7) << 4);
      gload_lds16(qb_bytes + ktile_byte + swz, (char*)&Ks[buf][0] + o);
    }
#pragma unroll
    for (int i = 0; i < 2; ++i) {
      const int o = tid * 16 + i * 4096;
      const int row = o >> 7;                       // d index
      const int colb = (o & 127) ^ ((row & 7) << 4);
      const char* src = vt_bytes + ((size_t)(bh * HD + row) * SEQ + ks0) * 2 + colb;
      gload_lds16(src, (char*)&Vt[buf][0] + o);
    }
  };

  float m_r[4] = {-1e30f, -1e30f, -1e30f, -1e30f};
  float l_r[4] = {0.f, 0.f, 0.f, 0.f};
  f32x4 o_acc[4] = {};

  stage(0, 0);
  asm volatile("s_waitcnt vmcnt(0) lgkmcnt(0)" ::: "memory");
  __builtin_amdgcn_sched_barrier(0);
  __builtin_amdgcn_s_barrier();
  __builtin_amdgcn_sched_barrier(0);

  for (int kt = 0; kt < 32; ++kt) {
    const int p = kt & 1;
    if (kt < 31) stage(kt + 1, p ^ 1);  // async; drained only at end barrier

    // ---- S = Q K^T ----
    f32x4 s_acc[4] = {};
#pragma unroll
    for (int ks = 0; ks < 2; ++ks) {
      const bf16x8 aq = *reinterpret_cast<const bf16x8*>(&Qs[(wid * 16 + c) * 72 + ks * 32 + g * 8]);
#pragma unroll
      for (int j = 0; j < 4; ++j) {
        const int krow = j * 16 + c;
        const int colb = (ks * 64 + g * 16) ^ ((krow & 7) << 4);
        const bf16x8 bk = *reinterpret_cast<const bf16x8*>((const char*)&Ks[p][0] + krow * 128 + colb);
        s_acc[j] = __builtin_amdgcn_mfma_f32_16x16x32_bf16(aq, bk, s_acc[j], 0, 0, 0);
      }
    }
#pragma unroll
    for (int j = 0; j < 4; ++j) s_acc[j] *= 0.015625f;  // SCALE^2 = 1/64 exact

    // ---- online softmax (row = g*4+r across 16 lanes of c) ----
    float pv[4][4];
    float alpha[4];
#pragma unroll
    for (int r = 0; r < 4; ++r) {
      float tm = fmaxf(fmaxf(s_acc[0][r], s_acc[1][r]), fmaxf(s_acc[2][r], s_acc[3][r]));
#pragma unroll
      for (int off = 1; off < 16; off <<= 1) tm = fmaxf(tm, __shfl_xor(tm, off, 16));
      const float mnew = fmaxf(m_r[r], tm);
      alpha[r] = __expf(m_r[r] - mnew);
      m_r[r] = mnew;
      float rs = 0.f;
#pragma unroll
      for (int j = 0; j < 4; ++j) { pv[j][r] = __expf(s_acc[j][r] - mnew); rs += pv[j][r]; }
#pragma unroll
      for (int off = 1; off < 16; off <<= 1) rs += __shfl_xor(rs, off, 16);
      l_r[r] = l_r[r] * alpha[r] + rs;
    }
#pragma unroll
    for (int dn = 0; dn < 4; ++dn)
#pragma unroll
      for (int r = 0; r < 4; ++r) o_acc[dn][r] *= alpha[r];

    // ---- P -> LDS (col-bit4 XOR by row-bit3: conflict-free write+read) ----
#pragma unroll
    for (int j = 0; j < 4; ++j)
#pragma unroll
      for (int r = 0; r < 4; ++r) {
        const int prow = wid * 16 + g * 4 + r;
        const int col = (j * 16 + c) ^ ((g >> 1) << 4);
        Ps[prow * 72 + col] = f2bf(pv[j][r]);
      }

    asm volatile("s_waitcnt lgkmcnt(0)" ::: "memory");  // Ps visible; vmcnt stays in flight
    __builtin_amdgcn_sched_barrier(0);
    __builtin_amdgcn_s_barrier();
    __builtin_amdgcn_sched_barrier(0);

    // ---- O += P V ----
#pragma unroll
    for (int ks = 0; ks < 2; ++ks) {
      const int arow = wid * 16 + c;
      const int acol = (ks * 32 + g * 8) ^ (((c >> 3) & 1) << 4);
      const bf16x8 ap = *reinterpret_cast<const bf16x8*>(&Ps[arow * 72 + acol]);
#pragma unroll
      for (int dn = 0; dn < 4; ++dn) {
        const int vrow = dn * 16 + c;
        const int colb = (ks * 64 + g * 16) ^ ((vrow & 7) << 4);
        const bf16x8 bv = *reinterpret_cast<const bf16x8*>((const char*)&Vt[p][0] + vrow * 128 + colb);
        o_acc[dn] = __builtin_amdgcn_mfma_f32_16x16x32_bf16(ap, bv, o_acc[dn], 0, 0, 0);
      }
    }

    // end barrier: own prefetch loads done + Ps free for next iter
    asm volatile("s_waitcnt vmcnt(0) lgkmcnt(0)" ::: "memory");
    __builtin_amdgcn_sched_barrier(0);
    __builtin_amdgcn_s_barrier();
    __builtin_amdgcn_sched_barrier(0);
  }

  {  // epilogue: normalize, store (B,S,D) bf16
    const int b = bh / NH, h = bh % NH;
#pragma unroll
    for (int dn = 0; dn < 4; ++dn)
#pragma unroll
      for (int r = 0; r < 4; ++r) {
        const int srow = qs0 + wid * 16 + g * 4 + r;
        const int col = h * HD + dn * 16 + c;
        ao[((size_t)b * SEQ + srow) * DM + col] = f2bf(o_acc[dn][r] / l_r[r]);
      }
  }
}

// ---------------------------------------------------------------------------
// Kernel 3: out = ao @ proj_w^T + proj_b  (M=8192, N=768, K=768), f32 out.
// ---------------------------------------------------------------------------
__global__ __launch_bounds__(256) void proj_kernel(
    const unsigned short* __restrict__ ao, const float* __restrict__ w,
    const float* __restrict__ bias, float* __restrict__ out) {
  __shared__ alignas(16) unsigned short As[128 * 40];
  __shared__ alignas(16) unsigned short Bs[128 * 40];
  const int tid = threadIdx.x;
  const int lane = tid & 63, wid = tid >> 6;
  const int wr = wid >> 1, wc = wid & 1;
  const int g = lane >> 4, c = lane & 15;
  const int m0 = blockIdx.x * 128, n0 = blockIdx.y * 128;

  f32x4 acc[4][4] = {};

  for (int k0 = 0; k0 < DM; k0 += 32) {
#pragma unroll
    for (int i = 0; i < 2; ++i) {  // A: bf16 copy
      const int idx = tid + i * 256;
      const int row = idx >> 2, kq = (idx & 3) << 3;
      *reinterpret_cast<bf16x8*>(&As[row * 40 + kq]) =
          *reinterpret_cast<const bf16x8*>(&ao[(m0 + row) * DM + k0 + kq]);
    }
#pragma unroll
    for (int i = 0; i < 4; ++i) {  // B: f32 -> bf16
      const int idx = tid + i * 256;
      const int row = idx >> 3, kq = (idx & 7) << 2;
      const float4 vw = *reinterpret_cast<const float4*>(&w[(n0 + row) * DM + k0 + kq]);
      *reinterpret_cast<ushort4*>(&Bs[row * 40 + kq]) =
          make_ushort4(f2bf(vw.x), f2bf(vw.y), f2bf(vw.z), f2bf(vw.w));
    }
    __syncthreads();
    bf16x8 a_f[4], b_f[4];
#pragma unroll
    for (int i = 0; i < 4; ++i) {
      a_f[i] = *reinterpret_cast<const bf16x8*>(&As[(wr * 64 + i * 16 + c) * 40 + g * 8]);
      b_f[i] = *reinterpret_cast<const bf16x8*>(&Bs[(wc * 64 + i * 16 + c) * 40 + g * 8]);
    }
#pragma unroll
    for (int ai = 0; ai < 4; ++ai)
#pragma unroll
      for (int ni = 0; ni < 4; ++ni)
        acc[ai][ni] = __builtin_amdgcn_mfma_f32_16x16x32_bf16(a_f[ai], b_f[ni], acc[ai][ni], 0, 0, 0);
    __syncthreads();
  }

#pragma unroll
  for (int ni = 0; ni < 4; ++ni) {
    const int n = n0 + wc * 64 + ni * 16 + c;
    const float bn = bias[n];
#pragma unroll
    for (int ai = 0; ai < 4; ++ai)
#pragma unroll
      for (int r = 0; r < 4; ++r) {
        const int m = m0 + wr * 64 + ai * 16 + g * 4 + r;
        out[(size_t)m * DM + n] = acc[ai][ni][r] + bn;
      }
  }
}

extern "C" void kernel_launch(void* const* d_in, const int* in_sizes, int n_in,
                              void* d_out, int out_size, void* d_ws, size_t ws_size,
                              hipStream_t stream) {
  const float* x = (const float*)d_in[0];
  const float* qkv_w = (const float*)d_in[1];
  const float* qkv_b = (const float*)d_in[2];
  const float* proj_w = (const float*)d_in[3];
  const float* proj_b = (const float*)d_in[4];
  float* out = (float*)d_out;

  const size_t elems = (size_t)4 * NH * SEQ * HD;  // 6291456
  unsigned short* qbuf = (unsigned short*)d_ws;
  unsigned short* vtbuf = qbuf + elems;
  unsigned short* aobuf = vtbuf + elems;

  qkv_kernel<<<dim3(64, 12), 256, 0, stream>>>(x, qkv_w, qkv_b, qbuf, vtbuf);
  attn_kernel<<<dim3(32, 48), 256, 0, stream>>>(qbuf, vtbuf, aobuf);
  proj_kernel<<<dim3(64, 6), 256, 0, stream>>>(aobuf, proj_w, proj_b, out);
}

// Round 3
// 195.032 us; speedup vs baseline: 1.7737x; 1.4280x over previous
//
#include <hip/hip_runtime.h>
#include <hip/hip_bf16.h>

#define NH 12
#define HD 64
#define SEQ 2048
#define DM 768

typedef __attribute__((ext_vector_type(8))) short bf16x8;
typedef __attribute__((ext_vector_type(4))) float f32x4;

static __device__ __forceinline__ unsigned short f2bf(float f) {
  unsigned int u = __float_as_uint(f);
  u += 0x7fff + ((u >> 16) & 1);   // round-to-nearest-even
  return (unsigned short)(u >> 16);
}

static __device__ __forceinline__ unsigned cvt_pk_bf16(float lo, float hi) {
  unsigned r;
  asm("v_cvt_pk_bf16_f32 %0, %1, %2" : "=v"(r) : "v"(lo), "v"(hi));
  return r;
}

static __device__ __forceinline__ void gload_lds16(const void* g, void* l) {
  __builtin_amdgcn_global_load_lds(
      (const __attribute__((address_space(1))) void*)g,
      (__attribute__((address_space(3))) void*)l, 16, 0, 0);
}

// q-store scale: sqrt(log2(e))/8 — folds both the 1/64 attention scale and
// the base-2 exp conversion into the (exactly-representable-op) bf16 q.
#define QSCALE 0.15014030f

// ---------------------------------------------------------------------------
// Kernel 1: qkv = x @ W^T + b (M=8192,N=1536,K=768). q stored (B,H,S,HD) bf16
// PRE-SCALED by QSCALE; v stored transposed (B,H,HD,S) bf16.
// ---------------------------------------------------------------------------
__global__ __launch_bounds__(256) void qkv_kernel(
    const float* __restrict__ x, const float* __restrict__ w,
    const float* __restrict__ bias,
    unsigned short* __restrict__ qb, unsigned short* __restrict__ vtb) {
  __shared__ alignas(16) unsigned short As[128 * 40];
  __shared__ alignas(16) unsigned short Bs[128 * 40];
  const int tid = threadIdx.x;
  const int lane = tid & 63, wid = tid >> 6;
  const int wr = wid >> 1, wc = wid & 1;
  const int g = lane >> 4, c = lane & 15;
  const int m0 = blockIdx.x * 128, n0 = blockIdx.y * 128;

  f32x4 acc[4][4] = {};

  for (int k0 = 0; k0 < DM; k0 += 32) {
#pragma unroll
    for (int i = 0; i < 4; ++i) {
      const int idx = tid + i * 256;
      const int row = idx >> 3, kq = (idx & 7) << 2;
      const float4 va = *reinterpret_cast<const float4*>(&x[(m0 + row) * DM + k0 + kq]);
      const float4 vw = *reinterpret_cast<const float4*>(&w[(n0 + row) * DM + k0 + kq]);
      *reinterpret_cast<ushort4*>(&As[row * 40 + kq]) =
          make_ushort4(f2bf(va.x), f2bf(va.y), f2bf(va.z), f2bf(va.w));
      *reinterpret_cast<ushort4*>(&Bs[row * 40 + kq]) =
          make_ushort4(f2bf(vw.x), f2bf(vw.y), f2bf(vw.z), f2bf(vw.w));
    }
    __syncthreads();
    bf16x8 a_f[4], b_f[4];
#pragma unroll
    for (int i = 0; i < 4; ++i) {
      a_f[i] = *reinterpret_cast<const bf16x8*>(&As[(wr * 64 + i * 16 + c) * 40 + g * 8]);
      b_f[i] = *reinterpret_cast<const bf16x8*>(&Bs[(wc * 64 + i * 16 + c) * 40 + g * 8]);
    }
#pragma unroll
    for (int ai = 0; ai < 4; ++ai)
#pragma unroll
      for (int ni = 0; ni < 4; ++ni)
        acc[ai][ni] = __builtin_amdgcn_mfma_f32_16x16x32_bf16(a_f[ai], b_f[ni], acc[ai][ni], 0, 0, 0);
    __syncthreads();
  }

#pragma unroll
  for (int ni = 0; ni < 4; ++ni) {
    const int n = n0 + wc * 64 + ni * 16 + c;
    const float bn = bias[n];
    if (n < DM) {  // q path: (B,H,S,HD), pre-scaled
      const int h = n >> 6, d = n & 63;
#pragma unroll
      for (int ai = 0; ai < 4; ++ai)
#pragma unroll
        for (int r = 0; r < 4; ++r) {
          const int m = m0 + wr * 64 + ai * 16 + g * 4 + r;
          const int bb = m >> 11, s = m & 2047;
          qb[(((size_t)(bb * NH + h)) * SEQ + s) * HD + d] = f2bf((acc[ai][ni][r] + bn) * QSCALE);
        }
    } else {  // v path: transposed (B,H,HD,S)
      const int nn = n - DM;
      const int h = nn >> 6, d = nn & 63;
#pragma unroll
      for (int ai = 0; ai < 4; ++ai) {
        const int m_base = m0 + wr * 64 + ai * 16 + g * 4;
        const int bb = m_base >> 11, s0 = m_base & 2047;
        ushort4 pk = make_ushort4(f2bf(acc[ai][ni][0] + bn), f2bf(acc[ai][ni][1] + bn),
                                  f2bf(acc[ai][ni][2] + bn), f2bf(acc[ai][ni][3] + bn));
        *reinterpret_cast<ushort4*>(
            &vtb[((size_t)(bb * NH + h) * HD + d) * SEQ + s0]) = pk;
      }
    }
  }
}

// ---------------------------------------------------------------------------
// Kernel 2: flash attention, Q == K (pre-scaled), base-2 online softmax.
// Swapped QK^T: S^T = mfma(K,Q) puts a full q-row in each lane -> in-register
// softmax (2 shfl per reduce). P redistributed to the PV B-frag layout via a
// wave-private 2KB LDS exchange (no barrier). One s_barrier + vmcnt(0)/iter.
// ---------------------------------------------------------------------------
__global__ __launch_bounds__(256) void attn_kernel(
    const unsigned short* __restrict__ qb, const unsigned short* __restrict__ vtb,
    unsigned short* __restrict__ ao) {
  __shared__ alignas(16) unsigned short Ks[2][64 * 64];   // linear + XOR swizzle
  __shared__ alignas(16) unsigned short Vt[2][64 * 64];   // V^T tile, same swizzle
  __shared__ alignas(16) unsigned int Xs[4][512];         // per-wave P exchange

  const int tid = threadIdx.x;
  const int lane = tid & 63, wid = tid >> 6;
  const int g = lane >> 4, c = lane & 15;
  const int bh = blockIdx.y;
  const int qs0 = blockIdx.x * 64;
  const size_t base = (size_t)bh * SEQ * HD;

  // Q fragment in registers for all 32 iters: lane (c,g) holds
  // Q[q = qs0 + wid*16 + c][d = 32ks + 8g .. +7]
  bf16x8 qf[2];
  {
    const unsigned short* qrow = &qb[base + (size_t)(qs0 + wid * 16 + c) * HD + g * 8];
    qf[0] = *reinterpret_cast<const bf16x8*>(qrow);
    qf[1] = *reinterpret_cast<const bf16x8*>(qrow + 32);
  }

  const char* qb_bytes = (const char*)qb;
  const char* vt_bytes = (const char*)vtb;
  auto stage = [&](int kt, int buf) {
    const int ks0 = kt * 64;
    const size_t ktile_byte = (base + (size_t)ks0 * HD) * 2;  // contiguous 8KB
#pragma unroll
    for (int i = 0; i < 2; ++i) {
      const int o = tid * 16 + i * 4096;
      const int swz = o ^ (((o >> 7) & 7) << 4);
      gload_lds16(qb_bytes + ktile_byte + swz, (char*)&Ks[buf][0] + o);
    }
#pragma unroll
    for (int i = 0; i < 2; ++i) {
      const int o = tid * 16 + i * 4096;
      const int row = o >> 7;  // d index
      const int colb = (o & 127) ^ ((row & 7) << 4);
      const char* src = vt_bytes + ((size_t)(bh * HD + row) * SEQ + ks0) * 2 + colb;
      gload_lds16(src, (char*)&Vt[buf][0] + o);
    }
  };

  float m_r = -1e30f, l_r = 0.f;
  f32x4 o_acc[4] = {};

  stage(0, 0);

  for (int kt = 0; kt < 32; ++kt) {
    const int p = kt & 1;
    asm volatile("s_waitcnt vmcnt(0)" ::: "memory");
    __builtin_amdgcn_s_barrier();
    __builtin_amdgcn_sched_barrier(0);
    if (kt < 31) stage(kt + 1, p ^ 1);  // overlaps this tile's compute

    // ---- S^T = K Q^T : lane holds S[k = 16j + 4g + r][q = c] ----
    f32x4 s_acc[4] = {};
    __builtin_amdgcn_s_setprio(1);
#pragma unroll
    for (int ks = 0; ks < 2; ++ks) {
#pragma unroll
      for (int j = 0; j < 4; ++j) {
        const int krow = j * 16 + c;
        const int colb = (ks * 64 + g * 16) ^ ((krow & 7) << 4);
        const bf16x8 bk = *reinterpret_cast<const bf16x8*>((const char*)&Ks[p][0] + krow * 128 + colb);
        s_acc[j] = __builtin_amdgcn_mfma_f32_16x16x32_bf16(bk, qf[ks], s_acc[j], 0, 0, 0);
      }
    }
    __builtin_amdgcn_s_setprio(0);

    // ---- in-register online softmax (base-2 logits) ----
    f32x4 mv = s_acc[0];
#pragma unroll
    for (int j = 1; j < 4; ++j)
#pragma unroll
      for (int r = 0; r < 4; ++r) mv[r] = fmaxf(mv[r], s_acc[j][r]);
    float tm = fmaxf(fmaxf(mv[0], mv[1]), fmaxf(mv[2], mv[3]));
    tm = fmaxf(tm, __shfl_xor(tm, 16));
    tm = fmaxf(tm, __shfl_xor(tm, 32));
    const float mnew = fmaxf(m_r, tm);
    const float alpha = __builtin_amdgcn_exp2f(m_r - mnew);
    m_r = mnew;

    float pf[4][4];
    f32x4 sv = {0.f, 0.f, 0.f, 0.f};
#pragma unroll
    for (int j = 0; j < 4; ++j)
#pragma unroll
      for (int r = 0; r < 4; ++r) {
        pf[j][r] = __builtin_amdgcn_exp2f(s_acc[j][r] - mnew);
        sv[r] += pf[j][r];
      }
    float rs = (sv[0] + sv[1]) + (sv[2] + sv[3]);
    rs += __shfl_xor(rs, 16);
    rs += __shfl_xor(rs, 32);
    l_r = l_r * alpha + rs;
#pragma unroll
    for (int dn = 0; dn < 4; ++dn) o_acc[dn] *= alpha;

    // ---- P exchange: (c,g) word (j,pr) -> (c,G) word (ks,u) ----
    // write addr (words): (g>>1)*256 + j*64 + c*4 + (g&1)*2 + pr
    unsigned* xw = &Xs[wid][(g >> 1) * 256 + c * 4 + (g & 1) * 2];
#pragma unroll
    for (int j = 0; j < 4; ++j) {
      uint2 wv = make_uint2(cvt_pk_bf16(pf[j][0], pf[j][1]),
                            cvt_pk_bf16(pf[j][2], pf[j][3]));
      *reinterpret_cast<uint2*>(xw + j * 64) = wv;
    }
    asm volatile("s_waitcnt lgkmcnt(0)" ::: "memory");
    __builtin_amdgcn_sched_barrier(0);
    // read addr: (g&1)*256 + (2ks + (g>>1))*64 + c*4, 4 consecutive words
    const unsigned* xr = &Xs[wid][(g & 1) * 256 + (g >> 1) * 64 + c * 4];
    const bf16x8 pB0 = *reinterpret_cast<const bf16x8*>(xr);
    const bf16x8 pB1 = *reinterpret_cast<const bf16x8*>(xr + 128);

    // ---- O^T += V^T P^T : lane holds O[q=c][d = 16dn + 4g + r] ----
    __builtin_amdgcn_s_setprio(1);
#pragma unroll
    for (int ks = 0; ks < 2; ++ks) {
      const bf16x8 pB = ks ? pB1 : pB0;
#pragma unroll
      for (int dn = 0; dn < 4; ++dn) {
        const int vrow = dn * 16 + c;
        const int colb = (ks * 64 + g * 16) ^ ((vrow & 7) << 4);
        const bf16x8 av = *reinterpret_cast<const bf16x8*>((const char*)&Vt[p][0] + vrow * 128 + colb);
        o_acc[dn] = __builtin_amdgcn_mfma_f32_16x16x32_bf16(av, pB, o_acc[dn], 0, 0, 0);
      }
    }
    __builtin_amdgcn_s_setprio(0);
  }

  // epilogue: normalize, packed b64 stores to (B,S,D) bf16
  {
    const float inv = __builtin_amdgcn_rcpf(l_r);
    const int b = bh / NH, h = bh % NH;
    const int q = qs0 + wid * 16 + c;
    unsigned short* orow = &ao[((size_t)b * SEQ + q) * DM + h * HD];
#pragma unroll
    for (int dn = 0; dn < 4; ++dn) {
      uint2 wv = make_uint2(cvt_pk_bf16(o_acc[dn][0] * inv, o_acc[dn][1] * inv),
                            cvt_pk_bf16(o_acc[dn][2] * inv, o_acc[dn][3] * inv));
      *reinterpret_cast<uint2*>(orow + dn * 16 + g * 4) = wv;
    }
  }
}

// ---------------------------------------------------------------------------
// Kernel 3: out = ao @ proj_w^T + proj_b  (M=8192, N=768, K=768), f32 out.
// ---------------------------------------------------------------------------
__global__ __launch_bounds__(256) void proj_kernel(
    const unsigned short* __restrict__ ao, const float* __restrict__ w,
    const float* __restrict__ bias, float* __restrict__ out) {
  __shared__ alignas(16) unsigned short As[128 * 40];
  __shared__ alignas(16) unsigned short Bs[128 * 40];
  const int tid = threadIdx.x;
  const int lane = tid & 63, wid = tid >> 6;
  const int wr = wid >> 1, wc = wid & 1;
  const int g = lane >> 4, c = lane & 15;
  const int m0 = blockIdx.x * 128, n0 = blockIdx.y * 128;

  f32x4 acc[4][4] = {};

  for (int k0 = 0; k0 < DM; k0 += 32) {
#pragma unroll
    for (int i = 0; i < 2; ++i) {  // A: bf16 copy
      const int idx = tid + i * 256;
      const int row = idx >> 2, kq = (idx & 3) << 3;
      *reinterpret_cast<bf16x8*>(&As[row * 40 + kq]) =
          *reinterpret_cast<const bf16x8*>(&ao[(m0 + row) * DM + k0 + kq]);
    }
#pragma unroll
    for (int i = 0; i < 4; ++i) {  // B: f32 -> bf16
      const int idx = tid + i * 256;
      const int row = idx >> 3, kq = (idx & 7) << 2;
      const float4 vw = *reinterpret_cast<const float4*>(&w[(n0 + row) * DM + k0 + kq]);
      *reinterpret_cast<ushort4*>(&Bs[row * 40 + kq]) =
          make_ushort4(f2bf(vw.x), f2bf(vw.y), f2bf(vw.z), f2bf(vw.w));
    }
    __syncthreads();
    bf16x8 a_f[4], b_f[4];
#pragma unroll
    for (int i = 0; i < 4; ++i) {
      a_f[i] = *reinterpret_cast<const bf16x8*>(&As[(wr * 64 + i * 16 + c) * 40 + g * 8]);
      b_f[i] = *reinterpret_cast<const bf16x8*>(&Bs[(wc * 64 + i * 16 + c) * 40 + g * 8]);
    }
#pragma unroll
    for (int ai = 0; ai < 4; ++ai)
#pragma unroll
      for (int ni = 0; ni < 4; ++ni)
        acc[ai][ni] = __builtin_amdgcn_mfma_f32_16x16x32_bf16(a_f[ai], b_f[ni], acc[ai][ni], 0, 0, 0);
    __syncthreads();
  }

#pragma unroll
  for (int ni = 0; ni < 4; ++ni) {
    const int n = n0 + wc * 64 + ni * 16 + c;
    const float bn = bias[n];
#pragma unroll
    for (int ai = 0; ai < 4; ++ai)
#pragma unroll
      for (int r = 0; r < 4; ++r) {
        const int m = m0 + wr * 64 + ai * 16 + g * 4 + r;
        out[(size_t)m * DM + n] = acc[ai][ni][r] + bn;
      }
  }
}

extern "C" void kernel_launch(void* const* d_in, const int* in_sizes, int n_in,
                              void* d_out, int out_size, void* d_ws, size_t ws_size,
                              hipStream_t stream) {
  const float* x = (const float*)d_in[0];
  const float* qkv_w = (const float*)d_in[1];
  const float* qkv_b = (const float*)d_in[2];
  const float* proj_w = (const float*)d_in[3];
  const float* proj_b = (const float*)d_in[4];
  float* out = (float*)d_out;

  const size_t elems = (size_t)4 * NH * SEQ * HD;  // 6291456
  unsigned short* qbuf = (unsigned short*)d_ws;
  unsigned short* vtbuf = qbuf + elems;
  unsigned short* aobuf = vtbuf + elems;

  qkv_kernel<<<dim3(64, 12), 256, 0, stream>>>(x, qkv_w, qkv_b, qbuf, vtbuf);
  attn_kernel<<<dim3(32, 48), 256, 0, stream>>>(qbuf, vtbuf, aobuf);
  proj_kernel<<<dim3(64, 6), 256, 0, stream>>>(aobuf, proj_w, proj_b, out);
}